// Round 1
// baseline (380.709 us; speedup 1.0000x reference)
//
#include <hip/hip_runtime.h>

// LSTM: B=2048, T=512, I=6, H=50, O=3. fp32 in/out, bf16 MFMA inner matmul.
//
// Structure: 256 WGs x 256 threads (1 WG/CU), NB=8 batch rows per WG.
// Per step: G^T = W' @ [h|x|1]^T via mfma_f32_16x16x32_bf16.
//   - Column permutation j' = 4*hidx + gate  =>  one lane's 4 acc regs hold
//     the i,f,g,o gates of one (batch,hidx) pair directly (C-layout:
//     col=lane&15 -> batch, row=quad*4+reg -> j'). No shuffles, 1 barrier/step.
//   - W' fragments (A-operand, M=j') loaded once into <=32 VGPRs/wave.
//   - [h|x|1|0] (K=64) lives in a 2-buffer LDS array; h written back as bf16
//     by the owning lanes each step; bias folded in via constant-1 column 56.
//   - c-state stays in lane registers for all 512 steps.
//   - x prefetched 4 steps deep in registers (wave 3, lanes 0..7).

#define L2E 1.44269504088896340736f

typedef float  f32x4  __attribute__((ext_vector_type(4)));
typedef short  s16x8  __attribute__((ext_vector_type(8)));   // 8 bf16 bit-patterns

__device__ __forceinline__ float fast_exp2(float x){ return __builtin_amdgcn_exp2f(x); }
__device__ __forceinline__ float fast_rcp (float x){ return __builtin_amdgcn_rcpf(x); }
__device__ __forceinline__ float sigm (float x){ return fast_rcp(1.0f + fast_exp2(-L2E * x)); }
__device__ __forceinline__ float tanhf_(float x){ return 1.0f - 2.0f * fast_rcp(1.0f + fast_exp2((2.0f*L2E) * x)); }

// float -> bf16 bits, round-to-nearest-even
__device__ __forceinline__ unsigned short f2bf(float f){
  unsigned u = __builtin_bit_cast(unsigned, f);
  u = (u + 0x7FFFu + ((u >> 16) & 1u)) >> 16;
  return (unsigned short)u;
}

constexpr int B_ = 2048, T_ = 512, I_ = 6, H_ = 50;
constexpr int NB = 8;     // batch rows per WG
constexpr int AP = 72;    // A-row pitch in bf16 elems (144 B, 16B-aligned, breaks pow2 stride)
constexpr int NT = 13;    // j' tiles: 13*16 = 208 >= 200

__global__ __launch_bounds__(256, 1)
void lstm_kernel(const float* __restrict__ x,
                 const float* __restrict__ W_ih, const float* __restrict__ W_hh,
                 const float* __restrict__ b_ih, const float* __restrict__ b_hh,
                 const float* __restrict__ W_out, const float* __restrict__ b_out,
                 float* __restrict__ out)
{
  __shared__ unsigned short Abuf[2][16 * AP];  // [h(50)|x(6)|1|0pad] per batch row, 16 rows (8 used)
  __shared__ float Hlast[NB][H_];

  const int tid  = threadIdx.x;
  const int lane = tid & 63;
  const int wave = tid >> 6;
  const int col  = lane & 15;   // MFMA N index = batch row
  const int quad = lane >> 4;   // MFMA row-group: hidx offset within tile; also A/B k-group
  const int b0   = blockIdx.x * NB;

  // ---- init LDS to zero ----
  unsigned short* ab = &Abuf[0][0];
  for (int i = tid; i < 2 * 16 * AP; i += 256) ab[i] = 0;
  __syncthreads();
  if (tid < NB) {
    Abuf[0][tid*AP + 56] = 0x3F80;  // 1.0 bf16 (bias column), persistent
    Abuf[1][tid*AP + 56] = 0x3F80;
    const float* xp = x + (size_t)(b0 + tid) * T_ * I_;  // x(t=0)
    #pragma unroll
    for (int i = 0; i < 6; i++) Abuf[0][tid*AP + 50 + i] = f2bf(xp[i]);
  }

  // ---- load weight fragments (A-operand, once) ----
  // lane holds W' row j' = jt*16 + col, k-slice quad*8..+7 (+32 for kh=1)
  // W'[j'][k]: j' = 4*hidx+gate -> source row = gate*50 + hidx
  s16x8 wfrag[4][2];
  #pragma unroll
  for (int ti = 0; ti < 4; ti++) {
    const int jt = wave + 4 * ti;           // wave-uniform
    if (jt < NT) {
      const int jp = jt * 16 + col;
      #pragma unroll
      for (int kh = 0; kh < 2; kh++) {
        s16x8 w;
        #pragma unroll
        for (int kk = 0; kk < 8; kk++) {
          const int k = kh * 32 + quad * 8 + kk;
          float v = 0.0f;
          if (jp < 200) {
            const int hh = jp >> 2, g = jp & 3;
            const int row = g * 50 + hh;
            if      (k < 50) v = W_hh[row * 50 + k];
            else if (k < 56) v = W_ih[row * 6 + (k - 50)];
            else if (k == 56) v = b_ih[row] + b_hh[row];
          }
          w[kk] = (short)f2bf(v);
        }
        wfrag[ti][kh] = w;
      }
    }
  }

  // ---- x prefetch ring: 4 steps deep (wave 3, lanes 0..7) ----
  const bool xduty = (wave == 3) && (lane < NB);
  float2 xr[4][3];
  if (xduty) {
    const float* xbase = x + (size_t)(b0 + lane) * T_ * I_;
    #pragma unroll
    for (int s = 1; s <= 4; s++) {      // x(s) -> slot s&3
      const float2* p = (const float2*)(xbase + (size_t)s * I_);
      xr[s & 3][0] = p[0]; xr[s & 3][1] = p[1]; xr[s & 3][2] = p[2];
    }
  }

  float c[4]    = {0.f, 0.f, 0.f, 0.f};
  float hreg[4] = {0.f, 0.f, 0.f, 0.f};
  const bool actlane = (col < NB);

  __syncthreads();

  #pragma unroll 4
  for (int t = 0; t < T_; t++) {
    const unsigned short* Ar = &Abuf[t & 1][0];
    unsigned short*       Aw = &Abuf[(t + 1) & 1][0];

    // write x(t+1) into next buffer (safe: prior readers of Aw synced at t-1's
    // barrier), then refill the freed ring slot with x(t+5) (deep prefetch)
    if (xduty) {
      if (t + 1 < T_) {
        const float2* s = xr[(t + 1) & 3];
        unsigned short* dst = Aw + lane * AP + 50;
        dst[0] = f2bf(s[0].x); dst[1] = f2bf(s[0].y);
        dst[2] = f2bf(s[1].x); dst[3] = f2bf(s[1].y);
        dst[4] = f2bf(s[2].x); dst[5] = f2bf(s[2].y);
      }
      if (t + 5 < T_) {
        const float2* p = (const float2*)(x + ((size_t)(b0 + lane) * T_ + (t + 5)) * I_);
        xr[(t + 1) & 3][0] = p[0]; xr[(t + 1) & 3][1] = p[1]; xr[(t + 1) & 3][2] = p[2];
      }
    }

    // B-operand fragments: B[k][n=batch] read from [b][k]-major LDS (k contiguous)
    const unsigned short* arow = Ar + col * AP;
    s16x8 bfr0 = *(const s16x8*)(arow + quad * 8);        // k = quad*8..+7
    s16x8 bfr1 = *(const s16x8*)(arow + 32 + quad * 8);   // k = 32+quad*8..+7

    f32x4 acc[4];
    #pragma unroll
    for (int ti = 0; ti < 4; ti++) {
      const int jt = wave + 4 * ti;
      if (jt < NT) {
        f32x4 a = {0.f, 0.f, 0.f, 0.f};
        a = __builtin_amdgcn_mfma_f32_16x16x32_bf16(wfrag[ti][0], bfr0, a, 0, 0, 0);
        a = __builtin_amdgcn_mfma_f32_16x16x32_bf16(wfrag[ti][1], bfr1, a, 0, 0, 0);
        acc[ti] = a;
      }
    }

    // activations: lane owns (b=col, hidx=4*jt+quad); acc regs = [i,f,g,o]
    #pragma unroll
    for (int ti = 0; ti < 4; ti++) {
      const int jt = wave + 4 * ti;
      if (jt < NT) {
        const int hidx = 4 * jt + quad;
        const float gi = sigm (acc[ti][0]);
        const float gf = sigm (acc[ti][1]);
        const float gg = tanhf_(acc[ti][2]);
        const float go = sigm (acc[ti][3]);
        const float cn = gf * c[ti] + gi * gg;
        c[ti] = cn;
        const float hn = go * tanhf_(cn);
        hreg[ti] = hn;
        if (actlane && hidx < H_) Aw[col * AP + hidx] = f2bf(hn);
      }
    }
    __syncthreads();  // writes to Aw visible; reads of Ar complete
  }

  // ---- epilogue: logits + softmax ----
  #pragma unroll
  for (int ti = 0; ti < 4; ti++) {
    const int jt = wave + 4 * ti;
    if (jt < NT) {
      const int hidx = 4 * jt + quad;
      if (actlane && hidx < H_) Hlast[col][hidx] = hreg[ti];  // fp32 h_last
    }
  }
  __syncthreads();

  if (tid < NB) {
    float l[3];
    #pragma unroll
    for (int o = 0; o < 3; o++) {
      float s = b_out[o];
      for (int k = 0; k < H_; k++) s += W_out[o * H_ + k] * Hlast[tid][k];
      l[o] = s;
    }
    const float m  = fmaxf(l[0], fmaxf(l[1], l[2]));
    const float e0 = fast_exp2((l[0] - m) * L2E);
    const float e1 = fast_exp2((l[1] - m) * L2E);
    const float e2 = fast_exp2((l[2] - m) * L2E);
    const float inv = fast_rcp(e0 + e1 + e2);
    float* op = out + (size_t)(b0 + tid) * 3;
    op[0] = e0 * inv; op[1] = e1 * inv; op[2] = e2 * inv;
  }
}

extern "C" void kernel_launch(void* const* d_in, const int* in_sizes, int n_in,
                              void* d_out, int out_size, void* d_ws, size_t ws_size,
                              hipStream_t stream) {
  const float* x     = (const float*)d_in[0];
  const float* W_ih  = (const float*)d_in[1];
  const float* W_hh  = (const float*)d_in[2];
  const float* b_ih  = (const float*)d_in[3];
  const float* b_hh  = (const float*)d_in[4];
  const float* W_out = (const float*)d_in[5];
  const float* b_out = (const float*)d_in[6];
  lstm_kernel<<<B_ / NB, 256, 0, stream>>>(x, W_ih, W_hh, b_ih, b_hh,
                                           W_out, b_out, (float*)d_out);
}